// Round 5
// baseline (1063.733 us; speedup 1.0000x reference)
//
#include <hip/hip_runtime.h>

#define DD 1024
#define NN 256
#define BB 64
#define EE 16
#define SS 16
#define HH 256
#define ES 256
#define BN 16384

typedef unsigned short u16;
typedef unsigned int u32;

__device__ __forceinline__ float b2f(u16 u) {
  union { u32 i; float f; } c; c.i = ((u32)u) << 16; return c.f;
}
__device__ __forceinline__ u16 f2b(float f) {
  union { float f; u32 i; } c; c.f = f;
  u32 i = c.i;
  u32 r = (i + 0x7FFFu + ((i >> 16) & 1u)) >> 16;
  return (u16)r;
}
__device__ __forceinline__ float blo(u32 u) {
  union { u32 i; float f; } c; c.i = u << 16; return c.f;
}
__device__ __forceinline__ float bhi(u32 u) {
  union { u32 i; float f; } c; c.i = u & 0xFFFF0000u; return c.f;
}

// block = 256 threads (4 waves). Sums v across the block, result broadcast.
__device__ __forceinline__ float bredsum(float v, float* red) {
  #pragma unroll
  for (int o = 32; o > 0; o >>= 1) v += __shfl_down(v, o, 64);
  __syncthreads();
  if ((threadIdx.x & 63) == 0) red[threadIdx.x >> 6] = v;
  __syncthreads();
  return red[0] + red[1] + red[2] + red[3];
}

// ---------------- K1: per-token LN stats + l2 factor ----------------
__global__ __launch_bounds__(256) void k_stats(
    const float* __restrict__ x, const float* __restrict__ gamma,
    const float* __restrict__ beta, const float* __restrict__ scale,
    float* __restrict__ mean_, float* __restrict__ rstd_,
    float* __restrict__ fct_) {
  __shared__ float red[4];
  int bn = blockIdx.x, t = threadIdx.x;
  float4 u = ((const float4*)(x + (size_t)bn * DD))[t];
  float s = u.x + u.y + u.z + u.w;
  float ss = u.x * u.x + u.y * u.y + u.z * u.z + u.w * u.w;
  s = bredsum(s, red);
  ss = bredsum(ss, red);
  float mean = s * (1.0f / DD);
  float var = ss * (1.0f / DD) - mean * mean;
  float rstd = rsqrtf(var + 1e-5f);
  float4 g = ((const float4*)gamma)[t];
  float4 be = ((const float4*)beta)[t];
  float x0 = (u.x - mean) * rstd * g.x + be.x;
  float x1 = (u.y - mean) * rstd * g.y + be.y;
  float x2 = (u.z - mean) * rstd * g.z + be.z;
  float x3 = (u.w - mean) * rstd * g.w + be.w;
  float s2 = x0 * x0 + x1 * x1 + x2 * x2 + x3 * x3;
  s2 = bredsum(s2, red);
  float f = scale[0] / fmaxf(sqrtf(s2), 1e-12f);
  if (t == 0) { mean_[bn] = mean; rstd_[bn] = rstd; fct_[bn] = f; }
}

// ---------------- K2: rmun[es] = 1 / max(||mu[:,es]||, eps) ----------------
__global__ __launch_bounds__(256) void k_rmun(
    const float* __restrict__ mu, float* __restrict__ rmun) {
  __shared__ float red[4];
  int es = blockIdx.x, t = threadIdx.x;
  float ss = 0.f;
  #pragma unroll
  for (int j = 0; j < 4; j++) {
    float v = mu[(size_t)(t + j * 256) * ES + es];
    ss += v * v;
  }
  ss = bredsum(ss, red);
  if (t == 0) rmun[es] = 1.0f / fmaxf(sqrtf(ss), 1e-12f);
}

// ---------------- K3: logits[bn,es] = fct[bn]*rmun[es]*(xn[bn,:].mu[:,es]) ------
__global__ __launch_bounds__(256) void k_logits(
    const float* __restrict__ x, const float* __restrict__ gamma,
    const float* __restrict__ beta, const float* __restrict__ mu,
    const float* __restrict__ mean_, const float* __restrict__ rstd_,
    const float* __restrict__ fct_, const float* __restrict__ rmun,
    float* __restrict__ logits) {
  __shared__ float xnT[DD][16];  // 64 KB, transposed recomputed-xn tile (fp32)
  int t = threadIdx.x;
  int row0 = blockIdx.x * 16;
  int r = t >> 4, dstart = (t & 15) * 64;
  float mn = mean_[row0 + r], rs = rstd_[row0 + r];
  const float* xs = x + (size_t)(row0 + r) * DD + dstart;
  const float* gs = gamma + dstart;
  const float* bs = beta + dstart;
  #pragma unroll
  for (int j = 0; j < 16; j++) {
    float4 xu = ((const float4*)xs)[j];
    float4 gu = ((const float4*)gs)[j];
    float4 bu = ((const float4*)bs)[j];
    int d = dstart + j * 4;
    xnT[d + 0][r] = (xu.x - mn) * rs * gu.x + bu.x;
    xnT[d + 1][r] = (xu.y - mn) * rs * gu.y + bu.y;
    xnT[d + 2][r] = (xu.z - mn) * rs * gu.z + bu.z;
    xnT[d + 3][r] = (xu.w - mn) * rs * gu.w + bu.w;
  }
  __syncthreads();
  int es = t;
  float acc[16];
  #pragma unroll
  for (int i = 0; i < 16; i++) acc[i] = 0.f;
  const float* mp = mu + es;
  for (int d = 0; d < DD; d++) {
    float m = mp[(size_t)d * ES];
    const float4* xp = (const float4*)&xnT[d][0];
    float4 a0 = xp[0], a1 = xp[1], a2 = xp[2], a3 = xp[3];
    acc[0] += a0.x * m; acc[1] += a0.y * m; acc[2] += a0.z * m; acc[3] += a0.w * m;
    acc[4] += a1.x * m; acc[5] += a1.y * m; acc[6] += a1.z * m; acc[7] += a1.w * m;
    acc[8] += a2.x * m; acc[9] += a2.y * m; acc[10] += a2.z * m; acc[11] += a2.w * m;
    acc[12] += a3.x * m; acc[13] += a3.y * m; acc[14] += a3.z * m; acc[15] += a3.w * m;
  }
  float fr = rmun[es];
  #pragma unroll
  for (int i = 0; i < 16; i++)
    logits[(size_t)(row0 + i) * ES + es] = acc[i] * fct_[row0 + i] * fr;
}

// ---------------- K4: fused dispatch-softmax + slot_in GEMM + expert MLP --------
// block (e, b): slot_out[b, e*16+s, :] for s in [0,16)
__global__ __launch_bounds__(256) void k_slotexp(
    const float* __restrict__ x, const float* __restrict__ gamma,
    const float* __restrict__ beta, const float* __restrict__ logits,
    const float* __restrict__ mean_, const float* __restrict__ rstd_,
    const float* __restrict__ w1, const float* __restrict__ b1,
    const float* __restrict__ w2, const float* __restrict__ b2,
    u16* __restrict__ slot_out) {
  __shared__ float wd_hT[4096];    // 16 KB: phases A/B = wd[n][j]; phase D = hT[h][s]
  __shared__ float statsL[2][NN];  // 2 KB
  __shared__ u16 siT[DD][16];      // 32 KB: slot_in tile (bf16), siT[d][s]
  __shared__ float wr[2][4][16];
  int t = threadIdx.x;
  int lane = t & 63, wv = t >> 6;
  int e = blockIdx.x, b = blockIdx.y;
  statsL[0][t] = mean_[(size_t)b * NN + t];
  statsL[1][t] = rstd_[(size_t)b * NN + t];
  // phase A: thread t = token n; softmax over n for the 16 es of expert e
  const float* lp = logits + ((size_t)b * NN + t) * ES + e * 16;
  float v[16];
  {
    const float4* lp4 = (const float4*)lp;
    #pragma unroll
    for (int q = 0; q < 4; q++) {
      float4 f = lp4[q];
      v[q * 4 + 0] = f.x; v[q * 4 + 1] = f.y;
      v[q * 4 + 2] = f.z; v[q * 4 + 3] = f.w;
    }
  }
  float r[16];
  #pragma unroll
  for (int j = 0; j < 16; j++) r[j] = v[j];
  #pragma unroll
  for (int o = 32; o > 0; o >>= 1)
    #pragma unroll
    for (int j = 0; j < 16; j++) r[j] = fmaxf(r[j], __shfl_down(r[j], o, 64));
  if (lane == 0)
    #pragma unroll
    for (int j = 0; j < 16; j++) wr[0][wv][j] = r[j];
  __syncthreads();
  #pragma unroll
  for (int j = 0; j < 16; j++) {
    float m = fmaxf(fmaxf(wr[0][0][j], wr[0][1][j]),
                    fmaxf(wr[0][2][j], wr[0][3][j]));
    v[j] = __expf(v[j] - m);
    r[j] = v[j];
  }
  #pragma unroll
  for (int o = 32; o > 0; o >>= 1)
    #pragma unroll
    for (int j = 0; j < 16; j++) r[j] += __shfl_down(r[j], o, 64);
  if (lane == 0)
    #pragma unroll
    for (int j = 0; j < 16; j++) wr[1][wv][j] = r[j];
  __syncthreads();
  #pragma unroll
  for (int j = 0; j < 16; j++) {
    float s = wr[1][0][j] + wr[1][1][j] + wr[1][2][j] + wr[1][3][j];
    wd_hT[t * 16 + j] = v[j] / s;
  }
  __syncthreads();
  // phase B: slot_in accumulation; thread t covers d0..d0+3, xn recomputed
  int d0 = t * 4;
  float4 gu = *(const float4*)(gamma + d0);
  float4 bu = *(const float4*)(beta + d0);
  float acc[16][4];
  #pragma unroll
  for (int j = 0; j < 16; j++)
    #pragma unroll
    for (int k = 0; k < 4; k++) acc[j][k] = 0.f;
  const float* xb = x + (size_t)b * NN * DD + d0;
  for (int n = 0; n < NN; n++) {
    float4 xu = *(const float4*)(xb + (size_t)n * DD);
    float mn = statsL[0][n], rs = statsL[1][n];
    float xv0 = (xu.x - mn) * rs * gu.x + bu.x;
    float xv1 = (xu.y - mn) * rs * gu.y + bu.y;
    float xv2 = (xu.z - mn) * rs * gu.z + bu.z;
    float xv3 = (xu.w - mn) * rs * gu.w + bu.w;
    float wv16[16];
    const float4* wp = (const float4*)&wd_hT[n * 16];
    *(float4*)&wv16[0] = wp[0]; *(float4*)&wv16[4] = wp[1];
    *(float4*)&wv16[8] = wp[2]; *(float4*)&wv16[12] = wp[3];
    #pragma unroll
    for (int j = 0; j < 16; j++) {
      acc[j][0] += wv16[j] * xv0; acc[j][1] += wv16[j] * xv1;
      acc[j][2] += wv16[j] * xv2; acc[j][3] += wv16[j] * xv3;
    }
  }
  // phase C: deposit slot_in tile (transposed, bf16) into LDS
  #pragma unroll
  for (int j = 0; j < 16; j++) {
    siT[d0 + 0][j] = f2b(acc[j][0]);
    siT[d0 + 1][j] = f2b(acc[j][1]);
    siT[d0 + 2][j] = f2b(acc[j][2]);
    siT[d0 + 3][j] = f2b(acc[j][3]);
  }
  __syncthreads();
  // phase D layer 1: thread t = h column
  float acc1[16];
  #pragma unroll
  for (int i = 0; i < 16; i++) acc1[i] = 0.f;
  const float* w1p = w1 + (size_t)e * DD * HH + t;
  for (int d = 0; d < DD; d++) {
    float w = w1p[(size_t)d * HH];
    const uint4* pp = (const uint4*)&siT[d][0];
    uint4 p0 = pp[0], p1 = pp[1];
    u32 pw[8];
    *(uint4*)&pw[0] = p0; *(uint4*)&pw[4] = p1;
    #pragma unroll
    for (int k = 0; k < 8; k++) {
      acc1[2 * k] += blo(pw[k]) * w;
      acc1[2 * k + 1] += bhi(pw[k]) * w;
    }
  }
  float b1v = b1[(size_t)e * HH + t];
  __syncthreads();  // all reads of wd (phase B) done before hT overwrite
  #pragma unroll
  for (int s = 0; s < 16; s++) {
    float z = acc1[s] + b1v;
    wd_hT[t * 16 + s] = 0.5f * z * (1.0f + erff(z * 0.70710678118654752f));
  }
  __syncthreads();
  // phase D layer 2: thread t covers d0..d0+3
  float acc2[16][4];
  #pragma unroll
  for (int s = 0; s < 16; s++)
    #pragma unroll
    for (int k = 0; k < 4; k++) acc2[s][k] = 0.f;
  const float* w2p = w2 + (size_t)e * HH * DD + d0;
  for (int h = 0; h < HH; h++) {
    float4 wu = *(const float4*)(w2p + (size_t)h * DD);
    float hv[16];
    const float4* hp = (const float4*)&wd_hT[h * 16];
    *(float4*)&hv[0] = hp[0]; *(float4*)&hv[4] = hp[1];
    *(float4*)&hv[8] = hp[2]; *(float4*)&hv[12] = hp[3];
    #pragma unroll
    for (int s = 0; s < 16; s++) {
      acc2[s][0] += hv[s] * wu.x; acc2[s][1] += hv[s] * wu.y;
      acc2[s][2] += hv[s] * wu.z; acc2[s][3] += hv[s] * wu.w;
    }
  }
  float4 b2u = *(const float4*)(b2 + (size_t)e * DD + d0);
  u16* ob = slot_out + ((size_t)b * ES + e * SS) * DD + d0;
  #pragma unroll
  for (int s = 0; s < 16; s++) {
    ushort4 o;
    o.x = f2b(acc2[s][0] + b2u.x); o.y = f2b(acc2[s][1] + b2u.y);
    o.z = f2b(acc2[s][2] + b2u.z); o.w = f2b(acc2[s][3] + b2u.w);
    *(ushort4*)(ob + (size_t)s * DD) = o;
  }
}

// ---------------- K5: fused combine-softmax (over es) + output GEMM -------------
// OUTPUT IS FP32 (reference returns float32; harness reads d_out as float*)
__global__ __launch_bounds__(256) void k_out(
    const u16* __restrict__ slot_out, const float* __restrict__ logits,
    float* __restrict__ out) {
  __shared__ float wc[ES][16];
  __shared__ float wr[2][4][16];
  int t = threadIdx.x;
  int lane = t & 63, wv = t >> 6;
  int b = blockIdx.y, n0 = blockIdx.x * 16;
  const float* lp = logits + ((size_t)b * NN + n0) * ES + t;
  float v[16];
  #pragma unroll
  for (int i = 0; i < 16; i++) v[i] = lp[(size_t)i * ES];
  float r[16];
  #pragma unroll
  for (int i = 0; i < 16; i++) r[i] = v[i];
  #pragma unroll
  for (int o = 32; o > 0; o >>= 1)
    #pragma unroll
    for (int i = 0; i < 16; i++) r[i] = fmaxf(r[i], __shfl_down(r[i], o, 64));
  if (lane == 0)
    #pragma unroll
    for (int i = 0; i < 16; i++) wr[0][wv][i] = r[i];
  __syncthreads();
  #pragma unroll
  for (int i = 0; i < 16; i++) {
    float m = fmaxf(fmaxf(wr[0][0][i], wr[0][1][i]),
                    fmaxf(wr[0][2][i], wr[0][3][i]));
    v[i] = __expf(v[i] - m);
    r[i] = v[i];
  }
  #pragma unroll
  for (int o = 32; o > 0; o >>= 1)
    #pragma unroll
    for (int i = 0; i < 16; i++) r[i] += __shfl_down(r[i], o, 64);
  if (lane == 0)
    #pragma unroll
    for (int i = 0; i < 16; i++) wr[1][wv][i] = r[i];
  __syncthreads();
  #pragma unroll
  for (int i = 0; i < 16; i++) {
    float s = wr[1][0][i] + wr[1][1][i] + wr[1][2][i] + wr[1][3][i];
    wc[t][i] = v[i] / s;
  }
  __syncthreads();
  int d0 = t * 4;
  float acc[16][4];
  #pragma unroll
  for (int j = 0; j < 16; j++)
    #pragma unroll
    for (int k = 0; k < 4; k++) acc[j][k] = 0.f;
  const u16* sb = slot_out + (size_t)b * ES * DD + d0;
  for (int es = 0; es < ES; es++) {
    ushort4 su = *(const ushort4*)(sb + (size_t)es * DD);
    float sx = b2f(su.x), sy = b2f(su.y), sz = b2f(su.z), sw = b2f(su.w);
    float cv[16];
    const float4* cpp = (const float4*)&wc[es][0];
    *(float4*)&cv[0] = cpp[0]; *(float4*)&cv[4] = cpp[1];
    *(float4*)&cv[8] = cpp[2]; *(float4*)&cv[12] = cpp[3];
    #pragma unroll
    for (int j = 0; j < 16; j++) {
      acc[j][0] += cv[j] * sx; acc[j][1] += cv[j] * sy;
      acc[j][2] += cv[j] * sz; acc[j][3] += cv[j] * sw;
    }
  }
  float* ob = out + ((size_t)b * NN + n0) * DD + d0;
  #pragma unroll
  for (int j = 0; j < 16; j++) {
    float4 o;
    o.x = acc[j][0]; o.y = acc[j][1]; o.z = acc[j][2]; o.w = acc[j][3];
    *(float4*)(ob + (size_t)j * DD) = o;
  }
}

extern "C" void kernel_launch(void* const* d_in, const int* in_sizes, int n_in,
                              void* d_out, int out_size, void* d_ws, size_t ws_size,
                              hipStream_t stream) {
  const float* x     = (const float*)d_in[0];
  const float* gamma = (const float*)d_in[1];
  const float* beta  = (const float*)d_in[2];
  const float* mu    = (const float*)d_in[3];
  const float* scale = (const float*)d_in[4];
  const float* w1    = (const float*)d_in[5];
  const float* b1    = (const float*)d_in[6];
  const float* w2    = (const float*)d_in[7];
  const float* b2    = (const float*)d_in[8];
  float* out = (float*)d_out;

  // Workspace layout — 50,532,352 B total (proven safe in round 3):
  //   slot_out bf16 [B,ES,D]  @ 0          (33,554,432)
  //   logits  fp32 [BN,ES]    @ 33,554,432 (16,777,216)
  //   mean    fp32 [BN]       @ 50,331,648 (65,536)
  //   rstd    fp32 [BN]       @ 50,397,184 (65,536)
  //   fct     fp32 [BN]       @ 50,462,720 (65,536)
  //   rmun    fp32 [ES]       @ 50,528,256 (4,096)
  const size_t WS_NEED = 50532352;
  // Diagnostic guard: if ws too small -> out stays 0 -> absmax == 3.027e-2.
  if (ws_size < WS_NEED) return;

  char* ws = (char*)d_ws;
  u16*   slot_out = (u16*)(ws);
  float* logits   = (float*)(ws + 33554432);
  float* mean_    = (float*)(ws + 50331648);
  float* rstd_    = (float*)(ws + 50397184);
  float* fct_     = (float*)(ws + 50462720);
  float* rmun     = (float*)(ws + 50528256);

  k_stats<<<BN, 256, 0, stream>>>(x, gamma, beta, scale, mean_, rstd_, fct_);
  k_rmun<<<ES, 256, 0, stream>>>(mu, rmun);
  k_logits<<<BN / 16, 256, 0, stream>>>(x, gamma, beta, mu, mean_, rstd_, fct_,
                                        rmun, logits);
  k_slotexp<<<dim3(EE, BB), 256, 0, stream>>>(x, gamma, beta, logits, mean_,
                                              rstd_, w1, b1, w2, b2, slot_out);
  k_out<<<dim3(16, BB), 256, 0, stream>>>(slot_out, logits, out);
}

// Round 6
// 566.601 us; speedup vs baseline: 1.8774x; 1.8774x over previous
//
#include <hip/hip_runtime.h>

#define DD 1024
#define NN 256
#define BB 64
#define EE 16
#define SS 16
#define HH 256
#define ES 256
#define BN 16384

typedef unsigned short u16;
typedef unsigned int u32;
typedef __attribute__((ext_vector_type(8))) short bf16x8;
typedef __attribute__((ext_vector_type(4))) float f32x4;

#define MFMA(a, b, c) __builtin_amdgcn_mfma_f32_16x16x32_bf16(a, b, c, 0, 0, 0)

__device__ __forceinline__ u16 f2b(float f) {
  union { float f; u32 i; } c; c.f = f;
  u32 i = c.i;
  u32 r = (i + 0x7FFFu + ((i >> 16) & 1u)) >> 16;
  return (u16)r;
}

// block = 256 threads (4 waves). Sums v across the block, result broadcast.
__device__ __forceinline__ float bredsum(float v, float* red) {
  #pragma unroll
  for (int o = 32; o > 0; o >>= 1) v += __shfl_down(v, o, 64);
  __syncthreads();
  if ((threadIdx.x & 63) == 0) red[threadIdx.x >> 6] = v;
  __syncthreads();
  return red[0] + red[1] + red[2] + red[3];
}

// ---------------- K1: per-token LN stats + l2 factor ----------------
__global__ __launch_bounds__(256) void k_stats(
    const float* __restrict__ x, const float* __restrict__ gamma,
    const float* __restrict__ beta, const float* __restrict__ scale,
    float* __restrict__ mean_, float* __restrict__ rstd_,
    float* __restrict__ fct_) {
  __shared__ float red[4];
  int bn = blockIdx.x, t = threadIdx.x;
  float4 u = ((const float4*)(x + (size_t)bn * DD))[t];
  float s = u.x + u.y + u.z + u.w;
  float ss = u.x * u.x + u.y * u.y + u.z * u.z + u.w * u.w;
  s = bredsum(s, red);
  ss = bredsum(ss, red);
  float mean = s * (1.0f / DD);
  float var = ss * (1.0f / DD) - mean * mean;
  float rstd = rsqrtf(var + 1e-5f);
  float4 g = ((const float4*)gamma)[t];
  float4 be = ((const float4*)beta)[t];
  float x0 = (u.x - mean) * rstd * g.x + be.x;
  float x1 = (u.y - mean) * rstd * g.y + be.y;
  float x2 = (u.z - mean) * rstd * g.z + be.z;
  float x3 = (u.w - mean) * rstd * g.w + be.w;
  float s2 = x0 * x0 + x1 * x1 + x2 * x2 + x3 * x3;
  s2 = bredsum(s2, red);
  float f = scale[0] / fmaxf(sqrtf(s2), 1e-12f);
  if (t == 0) { mean_[bn] = mean; rstd_[bn] = rstd; fct_[bn] = f; }
}

// ------- K2: rmun[es] = 1/max(||mu[:,es]||,eps); c3 = rmun*sum(g*mu); c4 = rmun*sum(be*mu)
__global__ __launch_bounds__(256) void k_rmun(
    const float* __restrict__ mu, const float* __restrict__ gamma,
    const float* __restrict__ beta, float* __restrict__ rmun,
    float* __restrict__ c3, float* __restrict__ c4) {
  __shared__ float red[4];
  int es = blockIdx.x, t = threadIdx.x;
  float ss = 0.f, s3 = 0.f, s4 = 0.f;
  #pragma unroll
  for (int j = 0; j < 4; j++) {
    int d = t + j * 256;
    float v = mu[(size_t)d * ES + es];
    ss += v * v;
    s3 += gamma[d] * v;
    s4 += beta[d] * v;
  }
  ss = bredsum(ss, red);
  s3 = bredsum(s3, red);
  s4 = bredsum(s4, red);
  if (t == 0) {
    float r = 1.0f / fmaxf(sqrtf(ss), 1e-12f);
    rmun[es] = r;
    c3[es] = s3 * r;
    c4[es] = s4 * r;
  }
}

// ------- K3: muT[es][d] = mu[d][es]*rmun[es]*gamma[d] (bf16, K-major) -------
__global__ __launch_bounds__(256) void k_mut(
    const float* __restrict__ mu, const float* __restrict__ gamma,
    const float* __restrict__ rmun, u16* __restrict__ muT) {
  __shared__ u16 L[256 * 70];
  int t = threadIdx.x;
  int d0 = blockIdx.x * 64;
  float rm = rmun[t];
  for (int i = 0; i < 64; i++) {
    int d = d0 + i;
    float gv = gamma[d];
    L[t * 70 + i] = f2b(mu[(size_t)d * ES + t] * rm * gv);
  }
  __syncthreads();
  u32 buf[32];
  #pragma unroll
  for (int k2 = 0; k2 < 32; k2++)
    buf[k2] = *(const u32*)&L[t * 70 + k2 * 2];
  u16* dst = muT + (size_t)t * DD + d0;
  #pragma unroll
  for (int k4 = 0; k4 < 8; k4++) {
    uint4 o;
    o.x = buf[k4 * 4]; o.y = buf[k4 * 4 + 1];
    o.z = buf[k4 * 4 + 2]; o.w = buf[k4 * 4 + 3];
    *(uint4*)(dst + k4 * 8) = o;
  }
}

// ------- K4: xT[d][bn] = bf16(x[bn][d]) — raw-x transpose -------
__global__ __launch_bounds__(256) void k_xt(
    const float* __restrict__ x, u16* __restrict__ xT) {
  __shared__ u16 L[256 * 70];
  int t = threadIdx.x;
  int bn0 = blockIdx.x * 64;
  for (int cch = 0; cch < 4; cch++) {
    __syncthreads();
    for (int r = 0; r < 64; r++)
      L[t * 70 + r] = f2b(x[(size_t)(bn0 + r) * DD + cch * 256 + t]);
    __syncthreads();
    u32 buf[32];
    #pragma unroll
    for (int k2 = 0; k2 < 32; k2++)
      buf[k2] = *(const u32*)&L[t * 70 + k2 * 2];
    u16* dst = xT + (size_t)(cch * 256 + t) * BN + bn0;
    #pragma unroll
    for (int k4 = 0; k4 < 8; k4++) {
      uint4 o;
      o.x = buf[k4 * 4]; o.y = buf[k4 * 4 + 1];
      o.z = buf[k4 * 4 + 2]; o.w = buf[k4 * 4 + 3];
      *(uint4*)(dst + k4 * 8) = o;
    }
  }
}

// ------- K5: generic per-expert transpose: src[e][R][C] fp32 -> dst[e][C][R] bf16
__global__ __launch_bounds__(256) void k_tr(
    const float* __restrict__ src, u16* __restrict__ dst, int R, int C) {
  __shared__ u16 T[64 * 70];
  int t = threadIdx.x;
  int e = blockIdx.y;
  int tR = R >> 6;
  int r0 = (blockIdx.x % tR) * 64;
  int c0 = (blockIdx.x / tR) * 64;
  #pragma unroll
  for (int i = 0; i < 16; i++) {
    int r = r0 + i * 4 + (t >> 6);
    int c = t & 63;
    T[c * 70 + i * 4 + (t >> 6)] = f2b(src[((size_t)e * R + r) * C + c0 + c]);
  }
  __syncthreads();
  int cl = t >> 2, rsg = (t & 3) * 16;
  u32 buf[8];
  #pragma unroll
  for (int k2 = 0; k2 < 8; k2++)
    buf[k2] = *(const u32*)&T[cl * 70 + rsg + k2 * 2];
  u16* dp = dst + ((size_t)e * C + c0 + cl) * R + r0 + rsg;
  uint4 o0, o1;
  o0.x = buf[0]; o0.y = buf[1]; o0.z = buf[2]; o0.w = buf[3];
  o1.x = buf[4]; o1.y = buf[5]; o1.z = buf[6]; o1.w = buf[7];
  *(uint4*)dp = o0;
  *(uint4*)(dp + 8) = o1;
}

// ------- K6: logitsT[es][bn] via MFMA: fct*(rs*(X.MU') - rs*mn*c3 + c4) -------
__global__ __launch_bounds__(256) void k_logits_mfma(
    const float* __restrict__ x, const u16* __restrict__ muT,
    const float* __restrict__ mean_, const float* __restrict__ rstd_,
    const float* __restrict__ fct_, const float* __restrict__ c3,
    const float* __restrict__ c4, float* __restrict__ logitsT) {
  __shared__ u16 xb[64 * 136];  // [64 bn][128 k] bf16, K-major, pad 8
  int t = threadIdx.x;
  int lane = t & 63, w = t >> 6, q = lane >> 4, m16 = lane & 15;
  int bn0 = blockIdx.x * 64;
  int es0 = blockIdx.y * 128 + w * 32;
  f32x4 z = {0.f, 0.f, 0.f, 0.f};
  f32x4 acc[2][4];
  #pragma unroll
  for (int mt = 0; mt < 2; mt++)
    #pragma unroll
    for (int nt = 0; nt < 4; nt++) acc[mt][nt] = z;
  int sr = t >> 5, cc = (t & 31) * 4;
  for (int kb = 0; kb < 8; kb++) {
    __syncthreads();
    #pragma unroll
    for (int it = 0; it < 8; it++) {
      int row = sr + it * 8;
      float4 v = *(const float4*)(x + (size_t)(bn0 + row) * DD + kb * 128 + cc);
      uint2 pk;
      pk.x = (u32)f2b(v.x) | ((u32)f2b(v.y) << 16);
      pk.y = (u32)f2b(v.z) | ((u32)f2b(v.w) << 16);
      *(uint2*)&xb[row * 136 + cc] = pk;
    }
    __syncthreads();
    #pragma unroll
    for (int ks = 0; ks < 4; ks++) {
      int k = ks * 32 + q * 8;
      bf16x8 a0 = *(const bf16x8*)(muT + (size_t)(es0 + m16) * DD + kb * 128 + k);
      bf16x8 a1 = *(const bf16x8*)(muT + (size_t)(es0 + 16 + m16) * DD + kb * 128 + k);
      #pragma unroll
      for (int nt = 0; nt < 4; nt++) {
        bf16x8 bb = *(const bf16x8*)&xb[(nt * 16 + m16) * 136 + k];
        acc[0][nt] = MFMA(a0, bb, acc[0][nt]);
        acc[1][nt] = MFMA(a1, bb, acc[1][nt]);
      }
    }
  }
  #pragma unroll
  for (int nt = 0; nt < 4; nt++) {
    int bn = bn0 + nt * 16 + m16;
    float fv = fct_[bn], rv = rstd_[bn], mv = mean_[bn];
    #pragma unroll
    for (int mt = 0; mt < 2; mt++)
      #pragma unroll
      for (int i = 0; i < 4; i++) {
        int es = es0 + mt * 16 + q * 4 + i;
        float val = fv * (rv * acc[mt][nt][i] - rv * mv * c3[es] + c4[es]);
        logitsT[(size_t)es * BN + bn] = val;
      }
  }
}

// ------- K7: fused dispatch-softmax + slot_in GEMM + expert MLP (all MFMA) -------
__global__ __launch_bounds__(256) void k_slotexp_mfma(
    const float* __restrict__ logitsT, const float* __restrict__ mean_,
    const float* __restrict__ rstd_, const u16* __restrict__ xT,
    const u16* __restrict__ w1T, const float* __restrict__ b1,
    const u16* __restrict__ w2T, const float* __restrict__ b2,
    const float* __restrict__ gamma, const float* __restrict__ beta,
    u16* __restrict__ slot_out) {
  __shared__ u16 wA[16 * 264];    // W' = dispatch*rstd, [16 s][256 n] K-major
  __shared__ u16 si[16 * 1032];   // slot_in [16 s][1024 d] K-major (reused for SO)
  __shared__ u16 hT[16 * 264];    // hidden [16 s][256 h] K-major
  __shared__ float c1L[16];
  int t = threadIdx.x;
  int lane = t & 63, w = t >> 6, q = lane >> 4, m16 = lane & 15;
  int blk = blockIdx.x;
  int e = (blk & 7) * 2 + ((blk >> 3) >> 6);  // XCD swizzle: same e -> same XCD
  int b = (blk >> 3) & 63;
  // ---- phase A: dispatch softmax over n (16 es rows of expert e) ----
  {
    int s = t >> 4, c = t & 15;
    const float* lrow = logitsT + (size_t)(e * 16 + s) * BN + b * 256 + c * 16;
    float lv[16];
    #pragma unroll
    for (int i2 = 0; i2 < 4; i2++) {
      float4 f = *(const float4*)(lrow + i2 * 4);
      lv[i2 * 4 + 0] = f.x; lv[i2 * 4 + 1] = f.y;
      lv[i2 * 4 + 2] = f.z; lv[i2 * 4 + 3] = f.w;
    }
    float mx = -1e30f;
    #pragma unroll
    for (int i = 0; i < 16; i++) mx = fmaxf(mx, lv[i]);
    #pragma unroll
    for (int o = 1; o < 16; o <<= 1) mx = fmaxf(mx, __shfl_xor(mx, o, 64));
    float sum = 0.f;
    #pragma unroll
    for (int i = 0; i < 16; i++) { lv[i] = __expf(lv[i] - mx); sum += lv[i]; }
    #pragma unroll
    for (int o = 1; o < 16; o <<= 1) sum += __shfl_xor(sum, o, 64);
    float inv = 1.0f / sum;
    float c1p = 0.f;
    u16 wp[16];
    #pragma unroll
    for (int i = 0; i < 16; i++) {
      int n = c * 16 + i;
      float wv = lv[i] * inv * rstd_[b * 256 + n];
      c1p += wv * mean_[b * 256 + n];
      wp[i] = f2b(wv);
    }
    #pragma unroll
    for (int o = 1; o < 16; o <<= 1) c1p += __shfl_xor(c1p, o, 64);
    if (c == 0) c1L[s] = c1p;
    #pragma unroll
    for (int i2 = 0; i2 < 4; i2++) {
      uint2 pk;
      pk.x = (u32)wp[i2 * 4] | ((u32)wp[i2 * 4 + 1] << 16);
      pk.y = (u32)wp[i2 * 4 + 2] | ((u32)wp[i2 * 4 + 3] << 16);
      *(uint2*)&wA[s * 264 + c * 16 + i2 * 4] = pk;
    }
  }
  __syncthreads();
  // ---- phase B: SI = W' . X^T (K=256 tokens), wave w owns d-strip 256 ----
  f32x4 z4 = {0.f, 0.f, 0.f, 0.f};
  {
    f32x4 acc[16];
    #pragma unroll
    for (int dt = 0; dt < 16; dt++) acc[dt] = z4;
    for (int ks = 0; ks < 8; ks++) {
      bf16x8 a = *(const bf16x8*)&wA[m16 * 264 + ks * 32 + q * 8];
      #pragma unroll
      for (int dt = 0; dt < 16; dt++) {
        const u16* bp = xT + (size_t)(w * 256 + dt * 16 + m16) * BN + b * 256 +
                        ks * 32 + q * 8;
        acc[dt] = MFMA(a, *(const bf16x8*)bp, acc[dt]);
      }
    }
    #pragma unroll
    for (int dt = 0; dt < 16; dt++) {
      int d = w * 256 + dt * 16 + m16;
      float gv = gamma[d], bev = beta[d];
      #pragma unroll
      for (int i = 0; i < 4; i++)
        si[(q * 4 + i) * 1032 + d] = f2b(gv * (acc[dt][i] - c1L[q * 4 + i]) + bev);
    }
  }
  __syncthreads();
  // ---- phase C: h = gelu(SI @ w1 + b1), wave w owns h-strip 64 ----
  {
    f32x4 acc1[4];
    #pragma unroll
    for (int ht = 0; ht < 4; ht++) acc1[ht] = z4;
    for (int ks = 0; ks < 32; ks++) {
      bf16x8 a = *(const bf16x8*)&si[m16 * 1032 + ks * 32 + q * 8];
      #pragma unroll
      for (int ht = 0; ht < 4; ht++) {
        const u16* bp = w1T + ((size_t)e * HH + w * 64 + ht * 16 + m16) * DD +
                        ks * 32 + q * 8;
        acc1[ht] = MFMA(a, *(const bf16x8*)bp, acc1[ht]);
      }
    }
    #pragma unroll
    for (int ht = 0; ht < 4; ht++) {
      int h = w * 64 + ht * 16 + m16;
      float b1v = b1[e * HH + h];
      #pragma unroll
      for (int i = 0; i < 4; i++) {
        float zz = acc1[ht][i] + b1v;
        hT[(q * 4 + i) * 264 + h] =
            f2b(0.5f * zz * (1.0f + erff(zz * 0.70710678118654752f)));
      }
    }
  }
  __syncthreads();
  // ---- phase D: SO = h @ w2 + b2, wave w owns d-strip 256 ----
  {
    f32x4 acc2[16];
    #pragma unroll
    for (int dt = 0; dt < 16; dt++) acc2[dt] = z4;
    for (int ks = 0; ks < 8; ks++) {
      bf16x8 a = *(const bf16x8*)&hT[m16 * 264 + ks * 32 + q * 8];
      #pragma unroll
      for (int dt = 0; dt < 16; dt++) {
        const u16* bp = w2T + ((size_t)e * DD + w * 256 + dt * 16 + m16) * HH +
                        ks * 32 + q * 8;
        acc2[dt] = MFMA(a, *(const bf16x8*)bp, acc2[dt]);
      }
    }
    #pragma unroll
    for (int dt = 0; dt < 16; dt++) {
      int d = w * 256 + dt * 16 + m16;
      float b2v = b2[e * DD + d];
      #pragma unroll
      for (int i = 0; i < 4; i++)
        si[(q * 4 + i) * 1032 + d] = f2b(acc2[dt][i] + b2v);
    }
  }
  __syncthreads();
  // ---- write slot_out rows coalesced ----
  {
    int s = t >> 4, seg = (t & 15) * 64;
    u16* dst = slot_out + ((size_t)b * ES + e * 16 + s) * DD + seg;
    #pragma unroll
    for (int k4 = 0; k4 < 8; k4++)
      *(uint4*)(dst + k4 * 8) = *(const uint4*)&si[s * 1032 + seg + k4 * 8];
  }
}

// ------- K8: fused combine-softmax + output GEMM (MFMA) -------
__global__ __launch_bounds__(256) void k_out_mfma(
    const u16* __restrict__ slot_out, const float* __restrict__ logitsT,
    float* __restrict__ out) {
  __shared__ u16 comb[32 * 264];  // [32 tokens][256 es] K-major bf16
  __shared__ u16 sot[64 * 264];   // [64 d][256 es] K-major bf16
  __shared__ float red[8][32];
  int t = threadIdx.x;
  int lane = t & 63, w = t >> 6, q = lane >> 4, m16 = lane & 15;
  int b = blockIdx.y, n0 = blockIdx.x * 32;
  // ---- phase A: combine softmax over 256 es for 32 tokens ----
  {
    int j = t & 31, ch = t >> 5;
    float lv[32];
    const float* base = logitsT + (size_t)(ch * 32) * BN + b * 256 + n0 + j;
    #pragma unroll
    for (int i = 0; i < 32; i++) lv[i] = base[(size_t)i * BN];
    float mx = -1e30f;
    #pragma unroll
    for (int i = 0; i < 32; i++) mx = fmaxf(mx, lv[i]);
    red[ch][j] = mx;
    __syncthreads();
    mx = red[0][j];
    #pragma unroll
    for (int k = 1; k < 8; k++) mx = fmaxf(mx, red[k][j]);
    __syncthreads();
    float sum = 0.f;
    #pragma unroll
    for (int i = 0; i < 32; i++) { lv[i] = __expf(lv[i] - mx); sum += lv[i]; }
    red[ch][j] = sum;
    __syncthreads();
    sum = 0.f;
    #pragma unroll
    for (int k = 0; k < 8; k++) sum += red[k][j];
    float inv = 1.0f / sum;
    #pragma unroll
    for (int i2 = 0; i2 < 8; i2++) {
      uint2 pk;
      pk.x = (u32)f2b(lv[i2 * 4] * inv) | ((u32)f2b(lv[i2 * 4 + 1] * inv) << 16);
      pk.y = (u32)f2b(lv[i2 * 4 + 2] * inv) | ((u32)f2b(lv[i2 * 4 + 3] * inv) << 16);
      *(uint2*)&comb[j * 264 + ch * 32 + i2 * 4] = pk;
    }
  }
  // ---- phase B: out-tile = comb @ SO over 16 d-chunks of 64 ----
  for (int dc = 0; dc < 16; dc++) {
    __syncthreads();
    {
      int es2 = (t & 127) * 2, dh = t >> 7;
      const u16* s0 = slot_out + ((size_t)b * ES + es2) * DD + dc * 64 + dh * 32;
      const u16* s1 = s0 + DD;
      #pragma unroll
      for (int k2 = 0; k2 < 8; k2++) {
        ushort4 r0 = *(const ushort4*)(s0 + k2 * 4);
        ushort4 r1 = *(const ushort4*)(s1 + k2 * 4);
        int dl = dh * 32 + k2 * 4;
        *(u32*)&sot[(dl + 0) * 264 + es2] = (u32)r0.x | ((u32)r1.x << 16);
        *(u32*)&sot[(dl + 1) * 264 + es2] = (u32)r0.y | ((u32)r1.y << 16);
        *(u32*)&sot[(dl + 2) * 264 + es2] = (u32)r0.z | ((u32)r1.z << 16);
        *(u32*)&sot[(dl + 3) * 264 + es2] = (u32)r0.w | ((u32)r1.w << 16);
      }
    }
    __syncthreads();
    f32x4 aA = {0.f, 0.f, 0.f, 0.f}, aB = {0.f, 0.f, 0.f, 0.f};
    #pragma unroll
    for (int ks = 0; ks < 8; ks++) {
      bf16x8 bb = *(const bf16x8*)&sot[(w * 16 + m16) * 264 + ks * 32 + q * 8];
      bf16x8 a0 = *(const bf16x8*)&comb[m16 * 264 + ks * 32 + q * 8];
      bf16x8 a1 = *(const bf16x8*)&comb[(16 + m16) * 264 + ks * 32 + q * 8];
      aA = MFMA(a0, bb, aA);
      aB = MFMA(a1, bb, aB);
    }
    int d = dc * 64 + w * 16 + m16;
    #pragma unroll
    for (int i = 0; i < 4; i++) {
      out[((size_t)b * NN + n0 + q * 4 + i) * DD + d] = aA[i];
      out[((size_t)b * NN + n0 + 16 + q * 4 + i) * DD + d] = aB[i];
    }
  }
}

extern "C" void kernel_launch(void* const* d_in, const int* in_sizes, int n_in,
                              void* d_out, int out_size, void* d_ws, size_t ws_size,
                              hipStream_t stream) {
  const float* x     = (const float*)d_in[0];
  const float* gamma = (const float*)d_in[1];
  const float* beta  = (const float*)d_in[2];
  const float* mu    = (const float*)d_in[3];
  const float* scale = (const float*)d_in[4];
  const float* w1    = (const float*)d_in[5];
  const float* b1    = (const float*)d_in[6];
  const float* w2    = (const float*)d_in[7];
  const float* b2    = (const float*)d_in[8];
  float* out = (float*)d_out;

  // ws (<= 50,531,328 B, within proven-safe 50,532,352):
  //   slot_out bf16 @0 (33,554,432) | logitsT fp32 [256 es][16384 bn] @33,554,432
  //   mean @50,331,648 | rstd @50,397,184 | fct @50,462,720 (64 KB each)
  //   rmun @50,528,256 | c3 @50,529,280 | c4 @50,530,304 (1 KB each)
  const size_t WS_NEED = 50531328;
  if (ws_size < WS_NEED) return;  // -> zeros -> absmax 3.027e-2 signals ws too small
  char* ws = (char*)d_ws;
  u16*   slot_out = (u16*)(ws);
  float* logitsT  = (float*)(ws + 33554432);
  float* mean_    = (float*)(ws + 50331648);
  float* rstd_    = (float*)(ws + 50397184);
  float* fct_     = (float*)(ws + 50462720);
  float* rmun     = (float*)(ws + 50528256);
  float* c3       = (float*)(ws + 50529280);
  float* c4       = (float*)(ws + 50530304);

  // d_out used as scratch until k_out_mfma overwrites it with the final fp32 out:
  //   xT bf16 [1024][16384] @0 (33,554,432) | w1T @33,554,432 (8,388,608)
  //   w2T @41,943,040 (8,388,608) | muT @50,331,648 (524,288)
  char* sc = (char*)d_out;
  u16* xT  = (u16*)(sc);
  u16* w1T = (u16*)(sc + 33554432);
  u16* w2T = (u16*)(sc + 41943040);
  u16* muT = (u16*)(sc + 50331648);

  k_stats<<<BN, 256, 0, stream>>>(x, gamma, beta, scale, mean_, rstd_, fct_);
  k_rmun<<<ES, 256, 0, stream>>>(mu, gamma, beta, rmun, c3, c4);
  k_mut<<<16, 256, 0, stream>>>(mu, gamma, rmun, muT);
  k_xt<<<BN / 64, 256, 0, stream>>>(x, xT);
  k_tr<<<dim3(64, EE), 256, 0, stream>>>(w1, w1T, DD, HH);  // w1T[e][h][d]
  k_tr<<<dim3(64, EE), 256, 0, stream>>>(w2, w2T, HH, DD);  // w2T[e][d][h]
  k_logits_mfma<<<dim3(BN / 64, 2), 256, 0, stream>>>(x, muT, mean_, rstd_, fct_,
                                                      c3, c4, logitsT);
  k_slotexp_mfma<<<EE * BB, 256, 0, stream>>>(logitsT, mean_, rstd_, xT, w1T, b1,
                                              w2T, b2, gamma, beta, slot_out);
  k_out_mfma<<<dim3(8, BB), 256, 0, stream>>>(slot_out, logitsT, out);
}